// Round 20
// baseline (63.632 us; speedup 1.0000x reference)
//
#include <hip/hip_runtime.h>
#include <math.h>

#define HIDDEN 1024
#define NL 9
#define LEAN_TAU 0.25f
#define LEAN_DELTA 0.35f
#define LCH 16
#define TFIX 512
#define TOKFIX 510  // T-2 compile-time: /TOKFIX lowers to magic-mul

typedef __attribute__((ext_vector_type(8))) short short8v;
typedef __attribute__((ext_vector_type(4))) float f32x4;
typedef __attribute__((ext_vector_type(4))) unsigned uint4v;
union frag_u { uint4v u; short8v s; };

// pack 2 fp32 -> 2 bf16 (truncation; validated end-to-end R16, absmax 0)
__device__ __forceinline__ unsigned pk2(float a, float b) {
  return (__float_as_uint(b) & 0xffff0000u) | (__float_as_uint(a) >> 16);
}

// ---------------- Kernel 1: K-split MFMA logits (R16 verbatim — best) -------
// ~54us ~= 124MB cold-read at ~2.3TB/s: the replay shares HBM with the
// harness reset()'s 512MB poison-fill writeback drain. Structure exonerated:
// R17 (pipelined), R18 (barrier-free 1-wave), R13/R14 (scalar variants) all
// land 55-62us; loads-only probe (R15) confirms the addressing is sound.
__global__ __launch_bounds__(256) void mfma_k(
    const float* __restrict__ hs, const float* __restrict__ w,
    const float* __restrict__ bias, const int* __restrict__ amask,
    float* __restrict__ e, int B) {
  const int nTok = B * TOKFIX;
  const int wave = threadIdx.x >> 6, lane = threadIdx.x & 63;
  const int g = lane >> 4, c = lane & 15;
  __shared__ unsigned short aw[4][16][264];
  __shared__ float4 cp[3][64];

  const int base = blockIdx.x * 16;
  {
    int b = base / TOKFIX, t = base - b * TOKFIX;
#pragma unroll
    for (int j = 0; j < 16; ++j) {
      const int tok = base + j;
      const float* src =
          hs + ((size_t)b * TFIX + ((tok < nTok) ? t : 0) + 1) * HIDDEN;
      const float4 f =
          *reinterpret_cast<const float4*>(src + wave * 256 + lane * 4);
      uint2 pk;
      pk.x = pk2(f.x, f.y);
      pk.y = pk2(f.z, f.w);
      *reinterpret_cast<uint2*>(&aw[wave][j][lane * 4]) = pk;
      if (++t >= TOKFIX) { t = 0; ++b; }
    }
  }
  frag_u bfrag[8];
  {
    const int brow = (c < NL) ? c : 0;
    const float* wp = w + (size_t)brow * HIDDEN + wave * 256 + g * 8;
#pragma unroll
    for (int s = 0; s < 8; ++s) {
      const float4 u0 = *reinterpret_cast<const float4*>(wp + s * 32);
      const float4 u1 = *reinterpret_cast<const float4*>(wp + s * 32 + 4);
      unsigned d0 = pk2(u0.x, u0.y), d1 = pk2(u0.z, u0.w);
      unsigned d2 = pk2(u1.x, u1.y), d3 = pk2(u1.z, u1.w);
      if (c >= NL) d0 = d1 = d2 = d3 = 0u;
      bfrag[s].u = uint4v{d0, d1, d2, d3};
    }
  }
  __syncthreads();

  f32x4 acc = {0.f, 0.f, 0.f, 0.f};
#pragma unroll
  for (int s = 0; s < 8; ++s) {
    const short8v a =
        *reinterpret_cast<const short8v*>(&aw[wave][c][s * 32 + g * 8]);
    acc = __builtin_amdgcn_mfma_f32_16x16x32_bf16(a, bfrag[s].s, acc, 0, 0, 0);
  }

  if (wave != 0) cp[wave - 1][lane] = *reinterpret_cast<float4*>(&acc);
  __syncthreads();
  if (wave == 0) {
#pragma unroll
    for (int k = 0; k < 3; ++k) {
      const float4 p = cp[k][lane];
      acc[0] += p.x; acc[1] += p.y; acc[2] += p.z; acc[3] += p.w;
    }
    const float bc = (c < NL) ? bias[c] : 0.f;
#pragma unroll
    for (int j = 0; j < 4; ++j) {
      const int tok = base + g * 4 + j;
      const int tokc = (tok < nTok) ? tok : 0;
      const int b = tokc / TOKFIX, t = tokc - b * TOKFIX;
      const float v = acc[j] + bc;
      float m1 = (c < NL) ? v : -1e30f, m2 = -1e30f;
#pragma unroll
      for (int off = 1; off < 16; off <<= 1) {
        const float om1 = __shfl_xor(m1, off);
        const float om2 = __shfl_xor(m2, off);
        const float hi = fmaxf(m1, om1);
        const float lo = fminf(m1, om1);
        m2 = fmaxf(lo, fmaxf(m2, om2));
        m1 = hi;
      }
      const bool unc = (m1 - m2 < LEAN_TAU) && (amask[b * TFIX + t + 1] != 0);
      const float vout = v + ((unc && c == 0) ? LEAN_DELTA : 0.f);
      if (c < NL && tok < nTok) e[(size_t)tok * NL + c] = vout;
    }
  }
}

// ---------------- Kernel 2: fused CRF + final mean (atomic) -----------------
// R19's fused chunk+combine, plus the -mean fold: lane0 atomicAdd's
// -llh_b/B straight into d_out (zeroed by a captured memset node). Third
// kernel and llh buffer eliminated.
__global__ __launch_bounds__(512) void crf_k(
    const float* __restrict__ e, const int* __restrict__ labels,
    const float* __restrict__ start_t, const float* __restrict__ end_t,
    const float* __restrict__ trans, float* __restrict__ out,
    int B, int T, int C) {
  const int TOK = T - 2;
  const int NSTEP = TOK - 1;  // 509
  const int b = blockIdx.x;
  const int tid = threadIdx.x;
  const int wave = tid >> 6, lane = tid & 63;

  __shared__ float esh[TOKFIX * NL];      // 18.4 KB (batch emission rows)
  __shared__ float Psh[32][NL * NL + 3];  // chunk matrices (+pad)
  __shared__ int lsh[TOKFIX];             // gold labels for t in [0,TOK)
  __shared__ float numsh;

  const float* eb = e + (size_t)b * TOK * NL;
  for (int i = tid; i < TOK * NL; i += 512) esh[i] = eb[i];
  for (int i = tid; i < TOK; i += 512) lsh[i] = labels[(size_t)b * T + 1 + i];
  __syncthreads();

  // ---- phase 1: per-chunk products (lane-group of 9 per chunk) ----
  const int sub = lane / 9, i9 = lane - sub * 9;
  const int c = wave * 7 + sub;
  if (sub < 7 && c < C) {
    float W[NL][NL];
#pragma unroll
    for (int k = 0; k < NL; ++k)
#pragma unroll
      for (int j = 0; j < NL; ++j) W[k][j] = __expf(trans[k * NL + j]);
    int len = NSTEP - c * LCH;
    if (len > LCH) len = LCH;
    const int t0 = 1 + c * LCH;
    float P[NL];
    {
      const int m0 = (lsh[t0] != -100);
#pragma unroll
      for (int j = 0; j < NL; ++j)
        P[j] = m0 ? (trans[i9 * NL + j] + esh[t0 * NL + j])
                  : ((i9 == j) ? 0.f : -1e30f);
    }
    for (int s = 1; s < len; ++s) {
      const int mt = (lsh[t0 + s] != -100);
      float mx = P[0];
#pragma unroll
      for (int k = 1; k < NL; ++k) mx = fmaxf(mx, P[k]);
      float E[NL];
#pragma unroll
      for (int k = 0; k < NL; ++k) E[k] = __expf(P[k] - mx);
      float Pn[NL];
#pragma unroll
      for (int j = 0; j < NL; ++j) {
        float sm = 0.f;
#pragma unroll
        for (int k = 0; k < NL; ++k) sm = fmaf(E[k], W[k][j], sm);
        Pn[j] = mx + __logf(sm) + esh[(t0 + s) * NL + j];
      }
#pragma unroll
      for (int j = 0; j < NL; ++j) P[j] = mt ? Pn[j] : P[j];
    }
#pragma unroll
    for (int j = 0; j < NL; ++j) Psh[c][i9 * NL + j] = P[j];
  }
  __syncthreads();

  // ---- phase 2: numerator (wave 1) + denominator fold (wave 0) ----
  if (wave == 1) {
    const int g0r = lsh[0];
    const int tg0 = (g0r == -100) ? 0 : g0r;
    float nsum = 0.f;
    int pack = -1;
    for (int t = 1 + lane; t < TOK; t += 64) {
      const int gr = lsh[t], pr = lsh[t - 1];
      if (gr != -100) {
        const int prev = (pr == -100) ? 0 : pr;
        nsum += trans[prev * NL + gr] + esh[t * NL + gr];
        pack = (t << 4) | gr;
      }
    }
#pragma unroll
    for (int off = 32; off; off >>= 1) {
      nsum += __shfl_xor(nsum, off);
      pack = max(pack, __shfl_xor(pack, off));
    }
    const int last = (pack < 0) ? tg0 : (pack & 15);
    if (lane == 0)
      numsh = start_t[tg0] + esh[tg0] + nsum + end_t[last];
  }
  float den = 0.f;
  if (wave == 0) {
    float alpha = (lane < NL) ? (start_t[lane] + esh[lane]) : -1e30f;
    for (int cc = 0; cc < C; ++cc) {
      float col[NL];
#pragma unroll
      for (int i = 0; i < NL; ++i)
        col[i] = (lane < NL) ? Psh[cc][i * NL + lane] : -1e30f;
      float s[NL], mx = -1e30f;
#pragma unroll
      for (int i = 0; i < NL; ++i) {
        const float ai = __shfl(alpha, i);
        s[i] = ai + col[i];
        mx = fmaxf(mx, s[i]);
      }
      float sum = 0.f;
#pragma unroll
      for (int i = 0; i < NL; ++i) sum += __expf(s[i] - mx);
      const float nx = mx + __logf(sum);
      alpha = (lane < NL) ? nx : -1e30f;
    }
    const float v = (lane < NL) ? (alpha + end_t[lane]) : -1e30f;
    float mx = v;
#pragma unroll
    for (int off = 32; off; off >>= 1) mx = fmaxf(mx, __shfl_xor(mx, off));
    float sum = (lane < NL) ? __expf(v - mx) : 0.f;
#pragma unroll
    for (int off = 32; off; off >>= 1) sum += __shfl_xor(sum, off);
    den = mx + __logf(sum);
  }
  __syncthreads();
  if (wave == 0 && lane == 0)
    atomicAdd(out, -(numsh - den) / (float)B);  // -mean, fused
}

extern "C" void kernel_launch(void* const* d_in, const int* in_sizes, int n_in,
                              void* d_out, int out_size, void* d_ws,
                              size_t ws_size, hipStream_t stream) {
  const float* hs     = (const float*)d_in[0];
  const float* w      = (const float*)d_in[1];
  const float* bias   = (const float*)d_in[2];
  const float* st     = (const float*)d_in[3];
  const float* et     = (const float*)d_in[4];
  const float* tr     = (const float*)d_in[5];
  const int*   amask  = (const int*)d_in[6];
  const int*   labels = (const int*)d_in[7];

  const int T = 512;
  const int B = in_sizes[6] / T;
  const int TOK = T - 2;
  const int C = (TOK - 1 + LCH - 1) / LCH;  // 32

  float* e = (float*)d_ws;                  // (B, TOK, 9)

  const int nTok = B * TOK;
  const int nTile = (nTok + 15) / 16;       // 2040
  hipMemsetAsync(d_out, 0, sizeof(float), stream);  // graph memset node
  mfma_k<<<nTile, 256, 0, stream>>>(hs, w, bias, amask, e, B);
  crf_k<<<B, 512, 0, stream>>>(e, labels, st, et, tr, (float*)d_out, B, T, C);
}

// Round 21
// 60.425 us; speedup vs baseline: 1.0531x; 1.0531x over previous
//
#include <hip/hip_runtime.h>
#include <math.h>

#define HIDDEN 1024
#define NL 9
#define LEAN_TAU 0.25f
#define LEAN_DELTA 0.35f
#define LCH 16
#define TFIX 512
#define TOKFIX 510  // T-2 compile-time: /TOKFIX lowers to magic-mul

typedef __attribute__((ext_vector_type(8))) short short8v;
typedef __attribute__((ext_vector_type(4))) float f32x4;
typedef __attribute__((ext_vector_type(4))) unsigned uint4v;
union frag_u { uint4v u; short8v s; };

// pack 2 fp32 -> 2 bf16 (truncation; validated end-to-end R16, absmax 0)
__device__ __forceinline__ unsigned pk2(float a, float b) {
  return (__float_as_uint(b) & 0xffff0000u) | (__float_as_uint(a) >> 16);
}

// ---------------- Kernel 1: K-split MFMA logits (R16 verbatim — best) -------
// ~54us ~= 124MB cold-read at ~2.3TB/s: the replay shares HBM with the
// harness reset()'s 512MB poison-fill writeback drain. Structure exonerated:
// R17 (pipelined), R18 (barrier-free 1-wave), R13/R14 (scalar variants) all
// land 55-62us; loads-only probe (R15) confirms the addressing is sound.
__global__ __launch_bounds__(256) void mfma_k(
    const float* __restrict__ hs, const float* __restrict__ w,
    const float* __restrict__ bias, const int* __restrict__ amask,
    float* __restrict__ e, int B) {
  const int nTok = B * TOKFIX;
  const int wave = threadIdx.x >> 6, lane = threadIdx.x & 63;
  const int g = lane >> 4, c = lane & 15;
  __shared__ unsigned short aw[4][16][264];
  __shared__ float4 cp[3][64];

  const int base = blockIdx.x * 16;
  {
    int b = base / TOKFIX, t = base - b * TOKFIX;
#pragma unroll
    for (int j = 0; j < 16; ++j) {
      const int tok = base + j;
      const float* src =
          hs + ((size_t)b * TFIX + ((tok < nTok) ? t : 0) + 1) * HIDDEN;
      const float4 f =
          *reinterpret_cast<const float4*>(src + wave * 256 + lane * 4);
      uint2 pk;
      pk.x = pk2(f.x, f.y);
      pk.y = pk2(f.z, f.w);
      *reinterpret_cast<uint2*>(&aw[wave][j][lane * 4]) = pk;
      if (++t >= TOKFIX) { t = 0; ++b; }
    }
  }
  frag_u bfrag[8];
  {
    const int brow = (c < NL) ? c : 0;
    const float* wp = w + (size_t)brow * HIDDEN + wave * 256 + g * 8;
#pragma unroll
    for (int s = 0; s < 8; ++s) {
      const float4 u0 = *reinterpret_cast<const float4*>(wp + s * 32);
      const float4 u1 = *reinterpret_cast<const float4*>(wp + s * 32 + 4);
      unsigned d0 = pk2(u0.x, u0.y), d1 = pk2(u0.z, u0.w);
      unsigned d2 = pk2(u1.x, u1.y), d3 = pk2(u1.z, u1.w);
      if (c >= NL) d0 = d1 = d2 = d3 = 0u;
      bfrag[s].u = uint4v{d0, d1, d2, d3};
    }
  }
  __syncthreads();

  f32x4 acc = {0.f, 0.f, 0.f, 0.f};
#pragma unroll
  for (int s = 0; s < 8; ++s) {
    const short8v a =
        *reinterpret_cast<const short8v*>(&aw[wave][c][s * 32 + g * 8]);
    acc = __builtin_amdgcn_mfma_f32_16x16x32_bf16(a, bfrag[s].s, acc, 0, 0, 0);
  }

  if (wave != 0) cp[wave - 1][lane] = *reinterpret_cast<float4*>(&acc);
  __syncthreads();
  if (wave == 0) {
#pragma unroll
    for (int k = 0; k < 3; ++k) {
      const float4 p = cp[k][lane];
      acc[0] += p.x; acc[1] += p.y; acc[2] += p.z; acc[3] += p.w;
    }
    const float bc = (c < NL) ? bias[c] : 0.f;
#pragma unroll
    for (int j = 0; j < 4; ++j) {
      const int tok = base + g * 4 + j;
      const int tokc = (tok < nTok) ? tok : 0;
      const int b = tokc / TOKFIX, t = tokc - b * TOKFIX;
      const float v = acc[j] + bc;
      float m1 = (c < NL) ? v : -1e30f, m2 = -1e30f;
#pragma unroll
      for (int off = 1; off < 16; off <<= 1) {
        const float om1 = __shfl_xor(m1, off);
        const float om2 = __shfl_xor(m2, off);
        const float hi = fmaxf(m1, om1);
        const float lo = fminf(m1, om1);
        m2 = fmaxf(lo, fmaxf(m2, om2));
        m1 = hi;
      }
      const bool unc = (m1 - m2 < LEAN_TAU) && (amask[b * TFIX + t + 1] != 0);
      const float vout = v + ((unc && c == 0) ? LEAN_DELTA : 0.f);
      if (c < NL && tok < nTok) e[(size_t)tok * NL + c] = vout;
    }
  }
}

// ---------------- Kernel 2: fused CRF (chunks + combine), 1 block/batch -----
// Stages the batch's e (18.4KB) + labels to LDS once; 8 waves x 7 lane-groups
// compute the 32 chunk 9x9 log-semiring products into LDS (no Pmat global
// round-trip); wave0 folds den, wave1 computes the numerator; one llh write.
__global__ __launch_bounds__(512) void crf_k(
    const float* __restrict__ e, const int* __restrict__ labels,
    const float* __restrict__ start_t, const float* __restrict__ end_t,
    const float* __restrict__ trans, float* __restrict__ llh,
    int B, int T, int C) {
  const int TOK = T - 2;
  const int NSTEP = TOK - 1;  // 509
  const int b = blockIdx.x;
  const int tid = threadIdx.x;
  const int wave = tid >> 6, lane = tid & 63;

  __shared__ float esh[TOKFIX * NL];      // 18.4 KB (batch emission rows)
  __shared__ float Psh[32][NL * NL + 3];  // chunk matrices (+pad)
  __shared__ int lsh[TOKFIX];             // gold labels for t in [0,TOK)
  __shared__ float numsh;

  const float* eb = e + (size_t)b * TOK * NL;
  for (int i = tid; i < TOK * NL; i += 512) esh[i] = eb[i];
  for (int i = tid; i < TOK; i += 512) lsh[i] = labels[(size_t)b * T + 1 + i];
  __syncthreads();

  // ---- phase 1: per-chunk products (lane-group of 9 per chunk) ----
  const int sub = lane / 9, i9 = lane - sub * 9;
  const int c = wave * 7 + sub;
  if (sub < 7 && c < C) {
    float W[NL][NL];
#pragma unroll
    for (int k = 0; k < NL; ++k)
#pragma unroll
      for (int j = 0; j < NL; ++j) W[k][j] = __expf(trans[k * NL + j]);
    int len = NSTEP - c * LCH;
    if (len > LCH) len = LCH;
    const int t0 = 1 + c * LCH;
    float P[NL];
    {
      const int m0 = (lsh[t0] != -100);
#pragma unroll
      for (int j = 0; j < NL; ++j)
        P[j] = m0 ? (trans[i9 * NL + j] + esh[t0 * NL + j])
                  : ((i9 == j) ? 0.f : -1e30f);
    }
    for (int s = 1; s < len; ++s) {
      const int mt = (lsh[t0 + s] != -100);
      float mx = P[0];
#pragma unroll
      for (int k = 1; k < NL; ++k) mx = fmaxf(mx, P[k]);
      float E[NL];
#pragma unroll
      for (int k = 0; k < NL; ++k) E[k] = __expf(P[k] - mx);
      float Pn[NL];
#pragma unroll
      for (int j = 0; j < NL; ++j) {
        float sm = 0.f;
#pragma unroll
        for (int k = 0; k < NL; ++k) sm = fmaf(E[k], W[k][j], sm);
        Pn[j] = mx + __logf(sm) + esh[(t0 + s) * NL + j];
      }
#pragma unroll
      for (int j = 0; j < NL; ++j) P[j] = mt ? Pn[j] : P[j];
    }
#pragma unroll
    for (int j = 0; j < NL; ++j) Psh[c][i9 * NL + j] = P[j];
  }
  __syncthreads();

  // ---- phase 2: numerator (wave 1) + denominator fold (wave 0) ----
  if (wave == 1) {
    const int g0r = lsh[0];
    const int tg0 = (g0r == -100) ? 0 : g0r;
    float nsum = 0.f;
    int pack = -1;
    for (int t = 1 + lane; t < TOK; t += 64) {
      const int gr = lsh[t], pr = lsh[t - 1];
      if (gr != -100) {
        const int prev = (pr == -100) ? 0 : pr;
        nsum += trans[prev * NL + gr] + esh[t * NL + gr];
        pack = (t << 4) | gr;
      }
    }
#pragma unroll
    for (int off = 32; off; off >>= 1) {
      nsum += __shfl_xor(nsum, off);
      pack = max(pack, __shfl_xor(pack, off));
    }
    const int last = (pack < 0) ? tg0 : (pack & 15);
    if (lane == 0)
      numsh = start_t[tg0] + esh[tg0] + nsum + end_t[last];
  }
  float den = 0.f;
  if (wave == 0) {
    float alpha = (lane < NL) ? (start_t[lane] + esh[lane]) : -1e30f;
    for (int cc = 0; cc < C; ++cc) {
      float col[NL];
#pragma unroll
      for (int i = 0; i < NL; ++i)
        col[i] = (lane < NL) ? Psh[cc][i * NL + lane] : -1e30f;
      float s[NL], mx = -1e30f;
#pragma unroll
      for (int i = 0; i < NL; ++i) {
        const float ai = __shfl(alpha, i);
        s[i] = ai + col[i];
        mx = fmaxf(mx, s[i]);
      }
      float sum = 0.f;
#pragma unroll
      for (int i = 0; i < NL; ++i) sum += __expf(s[i] - mx);
      const float nx = mx + __logf(sum);
      alpha = (lane < NL) ? nx : -1e30f;
    }
    const float v = (lane < NL) ? (alpha + end_t[lane]) : -1e30f;
    float mx = v;
#pragma unroll
    for (int off = 32; off; off >>= 1) mx = fmaxf(mx, __shfl_xor(mx, off));
    float sum = (lane < NL) ? __expf(v - mx) : 0.f;
#pragma unroll
    for (int off = 32; off; off >>= 1) sum += __shfl_xor(sum, off);
    den = mx + __logf(sum);
  }
  __syncthreads();
  if (wave == 0 && lane == 0) llh[b] = numsh - den;
}

// ---------------- Kernel 3: -mean(llh) ----------------
__global__ __launch_bounds__(64) void reduce_k(const float* __restrict__ llh,
                                               float* __restrict__ out, int B) {
  float v = 0.f;
  for (int i = threadIdx.x; i < B; i += 64) v += llh[i];
#pragma unroll
  for (int off = 32; off; off >>= 1) v += __shfl_xor(v, off);
  if (threadIdx.x == 0) out[0] = -v / (float)B;
}

extern "C" void kernel_launch(void* const* d_in, const int* in_sizes, int n_in,
                              void* d_out, int out_size, void* d_ws,
                              size_t ws_size, hipStream_t stream) {
  const float* hs     = (const float*)d_in[0];
  const float* w      = (const float*)d_in[1];
  const float* bias   = (const float*)d_in[2];
  const float* st     = (const float*)d_in[3];
  const float* et     = (const float*)d_in[4];
  const float* tr     = (const float*)d_in[5];
  const int*   amask  = (const int*)d_in[6];
  const int*   labels = (const int*)d_in[7];

  const int T = 512;
  const int B = in_sizes[6] / T;
  const int TOK = T - 2;
  const int C = (TOK - 1 + LCH - 1) / LCH;  // 32

  float* e   = (float*)d_ws;                // (B, TOK, 9)
  float* llh = e + (size_t)B * TOK * NL;    // (B,)

  const int nTok = B * TOK;
  const int nTile = (nTok + 15) / 16;       // 2040
  mfma_k<<<nTile, 256, 0, stream>>>(hs, w, bias, amask, e, B);
  crf_k<<<B, 512, 0, stream>>>(e, labels, st, et, tr, llh, B, T, C);
  reduce_k<<<1, 64, 0, stream>>>(llh, (float*)d_out, B);
}